// Round 10
// baseline (91.556 us; speedup 1.0000x reference)
//
#include <hip/hip_runtime.h>
#include <hip/hip_fp16.h>

#define KSZ 11
#define HALO 5
#define TILE 32     /* 32x32 output tile (R7-proven work-minimal shape) */
#define SMW 42      /* staged cols */
#define SMH 42      /* staged rows */
#define INSTR 43    /* input row stride, 8B units  (lin = 14448 B) */
#define VSTR 43     /* vbuf  row stride, 16B units (vbuf = 22016 B) */
#define THREADS 256

// Normalized 1-D Gaussian, sigma=1.5, K=11.
#define W0 1.0283800e-03f
#define W1 7.5987000e-03f
#define W2 3.6000800e-02f
#define W3 1.0936070e-01f
#define W4 2.1300550e-01f
#define W5 2.6601170e-01f

struct Pix8  { __half2 hx, hy; };             // staged input pixel (2ch x,y)
struct Pix16 { __half2 s0, s1, s2, s3; };     // V-blurred 4 signals

// V-blur one item (col c, output rows r0..r0+3) streaming lin rows r0..r0+13.
#define VBLUR(cc, rr0, A0, A1, A2, A3)                                  \
    do {                                                                \
        const Pix8* colp = &lin[(rr0) * INSTR + (cc)];                  \
        _Pragma("unroll") for (int i = 0; i < 14; ++i) {                \
            Pix8 p = colp[i * INSTR];                                   \
            __half2 hx = p.hx, hy = p.hy;                               \
            __half2 pq = __hfma2(hy, hy, __hmul2(hx, hx));              \
            __half2 qq = __hmul2(hx, hy);                               \
            _Pragma("unroll") for (int j = 0; j < 4; ++j) {             \
                const int t = i - j;                                    \
                if (t >= 0 && t < KSZ) {                                \
                    A0[j] = __hfma2(w2[t], hx, A0[j]);                  \
                    A1[j] = __hfma2(w2[t], hy, A1[j]);                  \
                    A2[j] = __hfma2(w2[t], pq, A2[j]);                  \
                    A3[j] = __hfma2(w2[t], qq, A3[j]);                  \
                }                                                       \
            }                                                           \
        }                                                               \
    } while (0)

// Stage-once + LDS-union fused SSIM at 32x32:
//   stage Pix8 -> V-pass batch A (items 256..335: write vbuf rows 24..31,
//   byte range disjoint from lin -> no barrier) -> V-pass batch B (items
//   0..255: accs in regs) -> barrier -> overwrite vbuf rows 0..23 ->
//   barrier -> H-pass (exact 256 items, b128) -> SSIM -> reduce.
//   LDS 22KB -> 7 blocks/CU (28 waves).
__global__ __launch_bounds__(THREADS) void ssim_tile_kernel(
    const float* __restrict__ x, const float* __restrict__ y,
    float* __restrict__ partial, int W, int H)
{
    __shared__ __align__(16) unsigned char smem_raw[TILE * VSTR * 16]; // 22016 B
    __shared__ float wsum[THREADS / 64];
    Pix8*  lin = (Pix8*)smem_raw;     // [SMH][INSTR], bytes 0..14448
    Pix16* vb  = (Pix16*)smem_raw;    // [TILE][VSTR], rows 24+ at bytes >=16512

    const float wf[KSZ] = {W0, W1, W2, W3, W4, W5, W4, W3, W2, W1, W0};
    __half2 w2[KSZ];
#pragma unroll
    for (int k = 0; k < KSZ; ++k) w2[k] = __float2half2_rn(wf[k]);
    const __half2 hz = __float2half2_rn(0.0f);

    const int tid = threadIdx.x;
    const int tilesPerRow = W / TILE;                  // 16
    const int tileR = (blockIdx.x / tilesPerRow) * TILE;
    const int tileC = (blockIdx.x % tilesPerRow) * TILE;
    const size_t plane = (size_t)W * (size_t)H;
    const size_t base0 = (size_t)blockIdx.y * 2 * plane;   // channel 0
    const size_t base1 = base0 + plane;                    // channel 1

    // ---- Phase 1: stage both channels of x,y (with halo) as Pix8 ----
    const bool interior = (tileR >= HALO) && (tileR + TILE + HALO <= H) &&
                          (tileC >= HALO) && (tileC + TILE + HALO <= W);
    if (interior) {
        const size_t org = (size_t)(tileR - HALO) * W + (tileC - HALO);
        for (int i = tid; i < SMH * SMW; i += THREADS) {
            int r = i / SMW, c = i - r * SMW;
            size_t g = org + (size_t)r * W + c;
            Pix8 p;
            p.hx = __floats2half2_rn(x[base0 + g], x[base1 + g]);
            p.hy = __floats2half2_rn(y[base0 + g], y[base1 + g]);
            lin[r * INSTR + c] = p;
        }
    } else {
        for (int i = tid; i < SMH * SMW; i += THREADS) {
            int r = i / SMW, c = i - r * SMW;
            int gr = tileR - HALO + r;
            int gc = tileC - HALO + c;
            float x0 = 0.f, x1 = 0.f, y0 = 0.f, y1 = 0.f;
            if (gr >= 0 && gr < H && gc >= 0 && gc < W) {
                size_t g = (size_t)gr * W + (size_t)gc;
                x0 = x[base0 + g]; x1 = x[base1 + g];
                y0 = y[base0 + g]; y1 = y[base1 + g];
            }
            Pix8 p;
            p.hx = __floats2half2_rn(x0, x1);
            p.hy = __floats2half2_rn(y0, y1);
            lin[r * INSTR + c] = p;
        }
    }
    __syncthreads();

    // ---- Phase 2a: V-items 256..335 (rows 24..31) -> write immediately ----
    // vbuf rows 24..31 occupy bytes 16512..22016, fully beyond lin (14448 B):
    // no overlap with any lin read -> no barrier needed around these writes.
    if (tid < 80) {
        const int it = 256 + tid;
        const int rg = it / SMW;          // 6 or 7
        const int c  = it - rg * SMW;
        const int r0 = rg << 2;           // 24 or 28
        __half2 e0[4] = {hz, hz, hz, hz}, e1[4] = {hz, hz, hz, hz};
        __half2 e2[4] = {hz, hz, hz, hz}, e3[4] = {hz, hz, hz, hz};
        VBLUR(c, r0, e0, e1, e2, e3);
#pragma unroll
        for (int j = 0; j < 4; ++j) {
            Pix16 o;
            o.s0 = e0[j]; o.s1 = e1[j]; o.s2 = e2[j]; o.s3 = e3[j];
            vb[(r0 + j) * VSTR + c] = o;
        }
    }

    // ---- Phase 2b: V-items 0..255 (rows 0..27), accs live across barrier ----
    __half2 a0[4] = {hz, hz, hz, hz}, a1[4] = {hz, hz, hz, hz};
    __half2 a2[4] = {hz, hz, hz, hz}, a3[4] = {hz, hz, hz, hz};
    const int brg = tid / SMW;            // 0..6
    const int bc  = tid - brg * SMW;      // 0..41
    const int br0 = brg << 2;             // 0,4,...,24
    VBLUR(bc, br0, a0, a1, a2, a3);
    __syncthreads();   // ALL lin reads done before overwriting rows 0..23

    // ---- Phase 3: write batch-B V-results (rows 0..27) ----
#pragma unroll
    for (int j = 0; j < 4; ++j) {
        Pix16 o;
        o.s0 = a0[j]; o.s1 = a1[j]; o.s2 = a2[j]; o.s3 = a3[j];
        vb[(br0 + j) * VSTR + bc] = o;
    }
    __syncthreads();

    // ---- Phase 4: H-pass, EXACTLY 256 items (row r, cols c0..c0+3) ----
    float bsum = 0.f;
    {
        const int r = tid >> 3;
        const int c0 = (tid & 7) << 2;
        const Pix16* row = &vb[r * VSTR + c0];

        __half2 b0[4] = {hz, hz, hz, hz}, b1[4] = {hz, hz, hz, hz};
        __half2 b2[4] = {hz, hz, hz, hz}, b3[4] = {hz, hz, hz, hz};
#pragma unroll
        for (int k = 0; k < 14; ++k) {
            Pix16 u = row[k];
#pragma unroll
            for (int j = 0; j < 4; ++j) {
                const int t = k - j;
                if (t >= 0 && t < KSZ) {
                    b0[j] = __hfma2(w2[t], u.s0, b0[j]);
                    b1[j] = __hfma2(w2[t], u.s1, b1[j]);
                    b2[j] = __hfma2(w2[t], u.s2, b2[j]);
                    b3[j] = __hfma2(w2[t], u.s3, b3[j]);
                }
            }
        }

        // ---- SSIM map (f32, per channel) ----
        const float c1 = 0.01f * 0.01f;
        const float c2 = 0.03f * 0.03f;
#pragma unroll
        for (int j = 0; j < 4; ++j) {
            float2 ux2 = __half22float2(b0[j]);
            float2 uy2 = __half22float2(b1[j]);
            float2 up2 = __half22float2(b2[j]);
            float2 uq2 = __half22float2(b3[j]);
#pragma unroll
            for (int ch = 0; ch < 2; ++ch) {
                float ux = ch ? ux2.y : ux2.x;
                float uy = ch ? uy2.y : uy2.x;
                float up = ch ? up2.y : up2.x;
                float uq = ch ? uq2.y : uq2.x;
                float sumsq = ux * ux + uy * uy;
                float vsum = up - sumsq;             // vx + vy
                float vxy = uq - ux * uy;
                float num = (2.f * ux * uy + c1) * (2.f * vxy + c2);
                float den = (sumsq + c1) * (vsum + c2);
                bsum += num * __builtin_amdgcn_rcpf(den + 1e-12f);
            }
        }
    }

    // ---- Wave shuffle reduce, cross-wave via LDS ----
#pragma unroll
    for (int off = 32; off > 0; off >>= 1) bsum += __shfl_down(bsum, off, 64);
    const int lane = tid & 63, wid = tid >> 6;
    if (lane == 0) wsum[wid] = bsum;
    __syncthreads();
    if (tid == 0) {
        float tot = 0.f;
#pragma unroll
        for (int i = 0; i < THREADS / 64; ++i) tot += wsum[i];
        partial[(size_t)blockIdx.y * gridDim.x + blockIdx.x] = tot;
    }
}

// Final deterministic reduction: n partials -> out[0] = 1 - sum/count
__global__ __launch_bounds__(256) void ssim_reduce_kernel(
    const float* __restrict__ partial, int n, float* __restrict__ out,
    double inv_count)
{
    __shared__ double ws[4];
    double s = 0.0;
    for (int i = threadIdx.x; i < n; i += 256) s += (double)partial[i];
#pragma unroll
    for (int off = 32; off > 0; off >>= 1) s += __shfl_down(s, off, 64);
    int lane = threadIdx.x & 63, wid = threadIdx.x >> 6;
    if (lane == 0) ws[wid] = s;
    __syncthreads();
    if (threadIdx.x == 0) {
        double tot = ws[0] + ws[1] + ws[2] + ws[3];
        out[0] = (float)(1.0 - tot * inv_count);
    }
}

extern "C" void kernel_launch(void* const* d_in, const int* in_sizes, int n_in,
                              void* d_out, int out_size, void* d_ws, size_t ws_size,
                              hipStream_t stream) {
    const float* x = (const float*)d_in[0];
    const float* y = (const float*)d_in[1];
    float* partial = (float*)d_ws;

    const int W = 512, H = 512;
    const int N = 32, C = 2;
    const int tilesPerPlane = (W / TILE) * (H / TILE); // 256
    // grid.y = N (batch); both channels packed per block.

    dim3 grid(tilesPerPlane, N);
    ssim_tile_kernel<<<grid, THREADS, 0, stream>>>(x, y, partial, W, H);

    const int nPartial = tilesPerPlane * N;     // 8192
    const double inv_count = 1.0 / ((double)N * C * W * H);
    ssim_reduce_kernel<<<1, 256, 0, stream>>>(partial, nPartial, (float*)d_out,
                                              inv_count);
}

// Round 11
// 75.447 us; speedup vs baseline: 1.2135x; 1.2135x over previous
//
#include <hip/hip_runtime.h>
#include <hip/hip_fp16.h>

#define KSZ 11
#define TILE 32       /* 32x32 output tile, 512/32=16 -> no row/col masking */
#define SMH 42        /* staged rows = TILE + 10 */
#define SST8 66       /* lin row stride in Pix8  units (528 B) */
#define SST16 33      /* hbuf row stride in Pix16 units (528 B) */
#define THREADS 256

// Normalized 1-D Gaussian, sigma=1.5, K=11.
#define W0 1.0283800e-03f
#define W1 7.5987000e-03f
#define W2 3.6000800e-02f
#define W3 1.0936070e-01f
#define W4 2.1300550e-01f
#define W5 2.6601170e-01f

struct Pix8   { __half2 hx, hy; };                 // staged input px (2ch x,y)
struct Pix8x2 { __half2 hx0, hy0, hx1, hy1; };     // two adjacent Pix8 (16B)
struct Pix16  { __half2 s0, s1, s2, s3; };         // H-blurred 4 signals (16B)

static __device__ inline __half2 pkrtz(float a, float b) {
    auto v = __builtin_amdgcn_cvt_pkrtz(a, b);     // 1 inst: v_cvt_pkrtz_f16_f32
    __half2 r;
    __builtin_memcpy(&r, &v, 4);
    return r;
}

// Row-aligned LDS union (528 B/row shared by lin row r and hbuf row r):
//   stage 48x42 Pix8 (b128 writes) -> barrier ->
//   H-pass (row-local: 8xb128 window read, then 4xb128 hbuf write into the
//   SAME row's bytes; wave owns 8 whole rows -> in-wave order = safe, no
//   barrier, no split) -> barrier -> V-pass (14xb128) + SSIM -> reduce.
//   LDS 22.2KB -> 7 blocks/CU. All LDS patterns bank-conflict-free.
__global__ __launch_bounds__(THREADS) void ssim_tile_kernel(
    const float* __restrict__ x, const float* __restrict__ y,
    float* __restrict__ partial, int W, int H)
{
    __shared__ __align__(16) unsigned char smem[SMH * 528];   // 22176 B
    __shared__ float wsum[THREADS / 64];
    Pix8*  lin = (Pix8*)smem;
    Pix16* hb  = (Pix16*)smem;

    const __half2 w2[KSZ] = {
        __float2half2_rn(W0), __float2half2_rn(W1), __float2half2_rn(W2),
        __float2half2_rn(W3), __float2half2_rn(W4), __float2half2_rn(W5),
        __float2half2_rn(W4), __float2half2_rn(W3), __float2half2_rn(W2),
        __float2half2_rn(W1), __float2half2_rn(W0)};
    const __half2 hz = __float2half2_rn(0.0f);

    const int tid = threadIdx.x;
    // XCD swizzle: per-plane, XCD k (= bx&7) owns contiguous tiles 32k..32k+31
    const int bx = blockIdx.x;                       // 0..255
    const int t  = ((bx & 7) << 5) | (bx >> 3);      // bijective remap
    const int tileR = (t >> 4) << 5;
    const int tileC = (t & 15) << 5;
    const size_t plane = (size_t)W * (size_t)H;
    const size_t base0 = (size_t)blockIdx.y * 2 * plane;   // channel 0
    const size_t base1 = base0 + plane;                    // channel 1

    // ---- Phase 1: stage 48 cols x 42 rows as Pix8 (strip base tileC-8) ----
    const bool interior = (tileR >= 5) && (tileR + 37 <= H) &&
                          (tileC >= 8) && (tileC + 40 <= W);
    for (int it = tid; it < SMH * 8; it += THREADS) {
        const int r = it >> 3;
        const int g = it & 7;
        const int c0 = 6 * g;                        // strip cols c0..c0+5
        Pix8 p[6];
        if (interior) {
            const size_t goff = (size_t)(tileR - 5 + r) * W + (tileC - 8 + c0);
            const float2* X0 = (const float2*)(x + base0 + goff);
            const float2* X1 = (const float2*)(x + base1 + goff);
            const float2* Y0 = (const float2*)(y + base0 + goff);
            const float2* Y1 = (const float2*)(y + base1 + goff);
#pragma unroll
            for (int m = 0; m < 3; ++m) {
                float2 a0 = X0[m], a1 = X1[m], b0 = Y0[m], b1 = Y1[m];
                p[2*m].hx   = pkrtz(a0.x, a1.x);
                p[2*m].hy   = pkrtz(b0.x, b1.x);
                p[2*m+1].hx = pkrtz(a0.y, a1.y);
                p[2*m+1].hy = pkrtz(b0.y, b1.y);
            }
        } else {
            const int gr = tileR - 5 + r;
#pragma unroll
            for (int m = 0; m < 6; ++m) {
                const int gc = tileC - 8 + c0 + m;
                float x0 = 0.f, x1 = 0.f, y0 = 0.f, y1 = 0.f;
                if (gr >= 0 && gr < H && gc >= 0 && gc < W) {
                    size_t gg = (size_t)gr * W + gc;
                    x0 = x[base0 + gg]; x1 = x[base1 + gg];
                    y0 = y[base0 + gg]; y1 = y[base1 + gg];
                }
                p[m].hx = pkrtz(x0, x1);
                p[m].hy = pkrtz(y0, y1);
            }
        }
        Pix8x2* dst = (Pix8x2*)&lin[r * SST8 + c0];  // 16B aligned (c0 even)
#pragma unroll
        for (int m = 0; m < 3; ++m) {
            Pix8x2 o;
            o.hx0 = p[2*m].hx;   o.hy0 = p[2*m].hy;
            o.hx1 = p[2*m+1].hx; o.hy1 = p[2*m+1].hy;
            dst[m] = o;
        }
    }
    __syncthreads();

    // ---- Phase 2: H-pass, 336 items; union-safe row-local overwrite ----
    for (int it = tid; it < SMH * 8; it += THREADS) {
        const int r = it >> 3;
        const int g = it & 7;
        const int c0 = g << 2;                       // output cols c0..c0+3
        // window strip slots [c0+2, c0+18); used slots [c0+3, c0+16]
        __half2 wx[16], wy[16];
        const Pix8x2* src = (const Pix8x2*)&lin[r * SST8 + (c0 + 2)];
#pragma unroll
        for (int k = 0; k < 8; ++k) {
            Pix8x2 u = src[k];
            wx[2*k]   = u.hx0; wy[2*k]   = u.hy0;
            wx[2*k+1] = u.hx1; wy[2*k+1] = u.hy1;
        }
        __half2 pp[16], qq[16];
#pragma unroll
        for (int k = 1; k < 15; ++k) {
            pp[k] = __hfma2(wy[k], wy[k], __hmul2(wx[k], wx[k]));  // x^2+y^2
            qq[k] = __hmul2(wx[k], wy[k]);                          // x*y
        }
        __half2 s0[4] = {hz, hz, hz, hz}, s1[4] = {hz, hz, hz, hz};
        __half2 s2[4] = {hz, hz, hz, hz}, s3[4] = {hz, hz, hz, hz};
#pragma unroll
        for (int k = 1; k < 15; ++k) {
#pragma unroll
            for (int j = 0; j < 4; ++j) {
                const int tt = k - 1 - j;
                if (tt >= 0 && tt < KSZ) {
                    s0[j] = __hfma2(w2[tt], wx[k], s0[j]);
                    s1[j] = __hfma2(w2[tt], wy[k], s1[j]);
                    s2[j] = __hfma2(w2[tt], pp[k], s2[j]);
                    s3[j] = __hfma2(w2[tt], qq[k], s3[j]);
                }
            }
        }
        // write hbuf row r (same row's bytes as lin row r -> safe in-wave)
        Pix16* o = &hb[r * SST16 + c0];
#pragma unroll
        for (int j = 0; j < 4; ++j) {
            Pix16 v;
            v.s0 = s0[j]; v.s1 = s1[j]; v.s2 = s2[j]; v.s3 = s3[j];
            o[j] = v;
        }
    }
    __syncthreads();

    // ---- Phase 3: V-pass + SSIM; EXACTLY 256 items (col c, rows r0..r0+3) --
    float bsum = 0.f;
    {
        const int c  = tid & 31;
        const int r0 = (tid >> 5) << 2;
        const Pix16* colp = &hb[r0 * SST16 + c];

        __half2 b0[4] = {hz, hz, hz, hz}, b1[4] = {hz, hz, hz, hz};
        __half2 b2[4] = {hz, hz, hz, hz}, b3[4] = {hz, hz, hz, hz};
#pragma unroll
        for (int k = 0; k < 14; ++k) {
            Pix16 u = colp[k * SST16];
#pragma unroll
            for (int j = 0; j < 4; ++j) {
                const int tt = k - j;
                if (tt >= 0 && tt < KSZ) {
                    b0[j] = __hfma2(w2[tt], u.s0, b0[j]);
                    b1[j] = __hfma2(w2[tt], u.s1, b1[j]);
                    b2[j] = __hfma2(w2[tt], u.s2, b2[j]);
                    b3[j] = __hfma2(w2[tt], u.s3, b3[j]);
                }
            }
        }

        const float c1 = 0.01f * 0.01f;
        const float c2 = 0.03f * 0.03f;
#pragma unroll
        for (int j = 0; j < 4; ++j) {
            float2 ux2 = __half22float2(b0[j]);
            float2 uy2 = __half22float2(b1[j]);
            float2 up2 = __half22float2(b2[j]);
            float2 uq2 = __half22float2(b3[j]);
#pragma unroll
            for (int ch = 0; ch < 2; ++ch) {
                float ux = ch ? ux2.y : ux2.x;
                float uy = ch ? uy2.y : uy2.x;
                float up = ch ? up2.y : up2.x;
                float uq = ch ? uq2.y : uq2.x;
                float sumsq = ux * ux + uy * uy;
                float vsum = up - sumsq;              // vx + vy
                float vxy = uq - ux * uy;
                float num = (2.f * ux * uy + c1) * (2.f * vxy + c2);
                float den = (sumsq + c1) * (vsum + c2);
                bsum += num * __builtin_amdgcn_rcpf(den + 1e-12f);
            }
        }
    }

    // ---- Wave shuffle reduce, cross-wave via LDS ----
#pragma unroll
    for (int off = 32; off > 0; off >>= 1) bsum += __shfl_down(bsum, off, 64);
    const int lane = tid & 63, wid = tid >> 6;
    if (lane == 0) wsum[wid] = bsum;
    __syncthreads();
    if (tid == 0) {
        float tot = 0.f;
#pragma unroll
        for (int i = 0; i < THREADS / 64; ++i) tot += wsum[i];
        partial[(size_t)blockIdx.y * gridDim.x + blockIdx.x] = tot;
    }
}

// Final deterministic reduction: n partials -> out[0] = 1 - sum/count
__global__ __launch_bounds__(256) void ssim_reduce_kernel(
    const float* __restrict__ partial, int n, float* __restrict__ out,
    double inv_count)
{
    __shared__ double ws[4];
    double s = 0.0;
    for (int i = threadIdx.x; i < n; i += 256) s += (double)partial[i];
#pragma unroll
    for (int off = 32; off > 0; off >>= 1) s += __shfl_down(s, off, 64);
    int lane = threadIdx.x & 63, wid = threadIdx.x >> 6;
    if (lane == 0) ws[wid] = s;
    __syncthreads();
    if (threadIdx.x == 0) {
        double tot = ws[0] + ws[1] + ws[2] + ws[3];
        out[0] = (float)(1.0 - tot * inv_count);
    }
}

extern "C" void kernel_launch(void* const* d_in, const int* in_sizes, int n_in,
                              void* d_out, int out_size, void* d_ws, size_t ws_size,
                              hipStream_t stream) {
    const float* x = (const float*)d_in[0];
    const float* y = (const float*)d_in[1];
    float* partial = (float*)d_ws;

    const int W = 512, H = 512;
    const int N = 32;
    const int tilesPerPlane = (W / TILE) * (H / TILE); // 256
    // grid.y = N (batch); both channels packed per block.

    dim3 grid(tilesPerPlane, N);
    ssim_tile_kernel<<<grid, THREADS, 0, stream>>>(x, y, partial, W, H);

    const int nPartial = tilesPerPlane * N;            // 8192
    const double inv_count = 1.0 / ((double)N * 2 * W * H);
    ssim_reduce_kernel<<<1, 256, 0, stream>>>(partial, nPartial, (float*)d_out,
                                              inv_count);
}

// Round 12
// 72.502 us; speedup vs baseline: 1.2628x; 1.0406x over previous
//
#include <hip/hip_runtime.h>
#include <hip/hip_fp16.h>

#define KSZ 11
#define TILE 32       /* 32x32 output tile, 512/32=16 -> no row/col masking */
#define SMH 42        /* staged rows = TILE + 10 */
#define SST8 66       /* lin row stride in Pix8  units (528 B) */
#define SST16 33      /* hbuf row stride in Pix16 units (528 B) */
#define THREADS 256

// Normalized 1-D Gaussian, sigma=1.5, K=11.
#define W0 1.0283800e-03f
#define W1 7.5987000e-03f
#define W2 3.6000800e-02f
#define W3 1.0936070e-01f
#define W4 2.1300550e-01f
#define W5 2.6601170e-01f

struct Pix8   { __half2 hx, hy; };                 // staged input px (2ch x,y)
struct Pix8x2 { __half2 hx0, hy0, hx1, hy1; };     // two adjacent Pix8 (16B)
struct Pix16  { __half2 s0, s1, s2, s3; };         // H-blurred 4 signals (16B)

static __device__ inline __half2 pkrtz(float a, float b) {
    auto v = __builtin_amdgcn_cvt_pkrtz(a, b);     // 1 inst: v_cvt_pkrtz_f16_f32
    __half2 r;
    __builtin_memcpy(&r, &v, 4);
    return r;
}

// Row-aligned LDS union (528 B/row shared by lin row r and hbuf row r):
//   stage 48x42 Pix8 (b128 writes) -> H-pass (NO barrier: stage item it and
//   H item it share the same tid map, and H row r is staged entirely by the
//   same 8-thread octet tids {8r..8r+7} (mod 256), which never straddles a
//   wave; same-wave LDS ops are ordered) -> barrier -> V-pass (14xb128) +
//   packed-f16 SSIM -> reduce.  LDS 22.2KB -> 7 blocks/CU.
__global__ __launch_bounds__(THREADS) void ssim_tile_kernel(
    const float* __restrict__ x, const float* __restrict__ y,
    float* __restrict__ partial, int W, int H)
{
    __shared__ __align__(16) unsigned char smem[SMH * 528];   // 22176 B
    __shared__ float wsum[THREADS / 64];
    Pix8*  lin = (Pix8*)smem;
    Pix16* hb  = (Pix16*)smem;

    const __half2 w2[KSZ] = {
        __float2half2_rn(W0), __float2half2_rn(W1), __float2half2_rn(W2),
        __float2half2_rn(W3), __float2half2_rn(W4), __float2half2_rn(W5),
        __float2half2_rn(W4), __float2half2_rn(W3), __float2half2_rn(W2),
        __float2half2_rn(W1), __float2half2_rn(W0)};
    const __half2 hz = __float2half2_rn(0.0f);

    const int tid = threadIdx.x;
    // XCD swizzle: per-plane, XCD k (= bx&7) owns contiguous tiles 32k..32k+31
    const int bx = blockIdx.x;                       // 0..255
    const int t  = ((bx & 7) << 5) | (bx >> 3);      // bijective remap
    const int tileR = (t >> 4) << 5;
    const int tileC = (t & 15) << 5;
    const size_t plane = (size_t)W * (size_t)H;
    const size_t base0 = (size_t)blockIdx.y * 2 * plane;   // channel 0
    const size_t base1 = base0 + plane;                    // channel 1

    // ---- Phase 1: stage 48 cols x 42 rows as Pix8 (strip base tileC-8) ----
    const bool interior = (tileR >= 5) && (tileR + 37 <= H) &&
                          (tileC >= 8) && (tileC + 40 <= W);
    for (int it = tid; it < SMH * 8; it += THREADS) {
        const int r = it >> 3;
        const int g = it & 7;
        const int c0 = 6 * g;                        // strip cols c0..c0+5
        Pix8 p[6];
        if (interior) {
            const size_t goff = (size_t)(tileR - 5 + r) * W + (tileC - 8 + c0);
            const float2* X0 = (const float2*)(x + base0 + goff);
            const float2* X1 = (const float2*)(x + base1 + goff);
            const float2* Y0 = (const float2*)(y + base0 + goff);
            const float2* Y1 = (const float2*)(y + base1 + goff);
#pragma unroll
            for (int m = 0; m < 3; ++m) {
                float2 a0 = X0[m], a1 = X1[m], b0 = Y0[m], b1 = Y1[m];
                p[2*m].hx   = pkrtz(a0.x, a1.x);
                p[2*m].hy   = pkrtz(b0.x, b1.x);
                p[2*m+1].hx = pkrtz(a0.y, a1.y);
                p[2*m+1].hy = pkrtz(b0.y, b1.y);
            }
        } else {
            const int gr = tileR - 5 + r;
#pragma unroll
            for (int m = 0; m < 6; ++m) {
                const int gc = tileC - 8 + c0 + m;
                float x0 = 0.f, x1 = 0.f, y0 = 0.f, y1 = 0.f;
                if (gr >= 0 && gr < H && gc >= 0 && gc < W) {
                    size_t gg = (size_t)gr * W + gc;
                    x0 = x[base0 + gg]; x1 = x[base1 + gg];
                    y0 = y[base0 + gg]; y1 = y[base1 + gg];
                }
                p[m].hx = pkrtz(x0, x1);
                p[m].hy = pkrtz(y0, y1);
            }
        }
        Pix8x2* dst = (Pix8x2*)&lin[r * SST8 + c0];  // 16B aligned (c0 even)
#pragma unroll
        for (int m = 0; m < 3; ++m) {
            Pix8x2 o;
            o.hx0 = p[2*m].hx;   o.hy0 = p[2*m].hy;
            o.hx1 = p[2*m+1].hx; o.hy1 = p[2*m+1].hy;
            dst[m] = o;
        }
    }
    // NO __syncthreads() here: H item it reads only row r = it>>3, which was
    // staged by the same 8-tid octet (same wave, ordered LDS ops). See header.

    // ---- Phase 2: H-pass, 336 items; union-safe row-local overwrite ----
    for (int it = tid; it < SMH * 8; it += THREADS) {
        const int r = it >> 3;
        const int g = it & 7;
        const int c0 = g << 2;                       // output cols c0..c0+3
        // window strip slots [c0+2, c0+18); used slots [c0+3, c0+16]
        __half2 wx[16], wy[16];
        const Pix8x2* src = (const Pix8x2*)&lin[r * SST8 + (c0 + 2)];
#pragma unroll
        for (int k = 0; k < 8; ++k) {
            Pix8x2 u = src[k];
            wx[2*k]   = u.hx0; wy[2*k]   = u.hy0;
            wx[2*k+1] = u.hx1; wy[2*k+1] = u.hy1;
        }
        __half2 pp[16], qq[16];
#pragma unroll
        for (int k = 1; k < 15; ++k) {
            pp[k] = __hfma2(wy[k], wy[k], __hmul2(wx[k], wx[k]));  // x^2+y^2
            qq[k] = __hmul2(wx[k], wy[k]);                          // x*y
        }
        __half2 s0[4] = {hz, hz, hz, hz}, s1[4] = {hz, hz, hz, hz};
        __half2 s2[4] = {hz, hz, hz, hz}, s3[4] = {hz, hz, hz, hz};
#pragma unroll
        for (int k = 1; k < 15; ++k) {
#pragma unroll
            for (int j = 0; j < 4; ++j) {
                const int tt = k - 1 - j;
                if (tt >= 0 && tt < KSZ) {
                    s0[j] = __hfma2(w2[tt], wx[k], s0[j]);
                    s1[j] = __hfma2(w2[tt], wy[k], s1[j]);
                    s2[j] = __hfma2(w2[tt], pp[k], s2[j]);
                    s3[j] = __hfma2(w2[tt], qq[k], s3[j]);
                }
            }
        }
        // write hbuf row r (same row's bytes as lin row r -> safe in-wave)
        Pix16* o = &hb[r * SST16 + c0];
#pragma unroll
        for (int j = 0; j < 4; ++j) {
            Pix16 v;
            v.s0 = s0[j]; v.s1 = s1[j]; v.s2 = s2[j]; v.s3 = s3[j];
            o[j] = v;
        }
    }
    __syncthreads();

    // ---- Phase 3: V-pass + packed-f16 SSIM; 256 items (col, 4 rows) ----
    float bsum;
    {
        const int c  = tid & 31;
        const int r0 = (tid >> 5) << 2;
        const Pix16* colp = &hb[r0 * SST16 + c];

        __half2 b0[4] = {hz, hz, hz, hz}, b1[4] = {hz, hz, hz, hz};
        __half2 b2[4] = {hz, hz, hz, hz}, b3[4] = {hz, hz, hz, hz};
#pragma unroll
        for (int k = 0; k < 14; ++k) {
            Pix16 u = colp[k * SST16];
#pragma unroll
            for (int j = 0; j < 4; ++j) {
                const int tt = k - j;
                if (tt >= 0 && tt < KSZ) {
                    b0[j] = __hfma2(w2[tt], u.s0, b0[j]);
                    b1[j] = __hfma2(w2[tt], u.s1, b1[j]);
                    b2[j] = __hfma2(w2[tt], u.s2, b2[j]);
                    b3[j] = __hfma2(w2[tt], u.s3, b3[j]);
                }
            }
        }

        // Packed-f16 SSIM: both channels per instr. c1 absorption (1e-4 vs
        // f16 ulp@0.5) cancels to 1st order between num and den; den stays
        // f16-normal (>=7e-5) so h2rcp is safe; 1e-12 dropped (underflows).
        const __half2 c1h  = __float2half2_rn(1.0e-4f);
        const __half2 c2h  = __float2half2_rn(9.0e-4f);
        const __half2 twoh = __float2half2_rn(2.0f);
        __half2 acc2 = hz;
#pragma unroll
        for (int j = 0; j < 4; ++j) {
            __half2 ux = b0[j], uy = b1[j], up = b2[j], uq = b3[j];
            __half2 uxuy  = __hmul2(ux, uy);
            __half2 sumsq = __hfma2(ux, ux, __hmul2(uy, uy));
            __half2 vsum  = __hsub2(up, sumsq);            // vx + vy
            __half2 vxy   = __hsub2(uq, uxuy);
            __half2 num   = __hmul2(__hfma2(twoh, uxuy, c1h),
                                    __hfma2(twoh, vxy, c2h));
            __half2 den   = __hmul2(__hadd2(sumsq, c1h), __hadd2(vsum, c2h));
            acc2 = __hfma2(num, h2rcp(den), acc2);
        }
        float2 af = __half22float2(acc2);
        bsum = af.x + af.y;
    }

    // ---- Wave shuffle reduce, cross-wave via LDS ----
#pragma unroll
    for (int off = 32; off > 0; off >>= 1) bsum += __shfl_down(bsum, off, 64);
    const int lane = tid & 63, wid = tid >> 6;
    if (lane == 0) wsum[wid] = bsum;
    __syncthreads();
    if (tid == 0) {
        float tot = 0.f;
#pragma unroll
        for (int i = 0; i < THREADS / 64; ++i) tot += wsum[i];
        partial[(size_t)blockIdx.y * gridDim.x + blockIdx.x] = tot;
    }
}

// Final deterministic reduction: n partials -> out[0] = 1 - sum/count
__global__ __launch_bounds__(256) void ssim_reduce_kernel(
    const float* __restrict__ partial, int n, float* __restrict__ out,
    double inv_count)
{
    __shared__ double ws[4];
    double s = 0.0;
    for (int i = threadIdx.x; i < n; i += 256) s += (double)partial[i];
#pragma unroll
    for (int off = 32; off > 0; off >>= 1) s += __shfl_down(s, off, 64);
    int lane = threadIdx.x & 63, wid = threadIdx.x >> 6;
    if (lane == 0) ws[wid] = s;
    __syncthreads();
    if (threadIdx.x == 0) {
        double tot = ws[0] + ws[1] + ws[2] + ws[3];
        out[0] = (float)(1.0 - tot * inv_count);
    }
}

extern "C" void kernel_launch(void* const* d_in, const int* in_sizes, int n_in,
                              void* d_out, int out_size, void* d_ws, size_t ws_size,
                              hipStream_t stream) {
    const float* x = (const float*)d_in[0];
    const float* y = (const float*)d_in[1];
    float* partial = (float*)d_ws;

    const int W = 512, H = 512;
    const int N = 32;
    const int tilesPerPlane = (W / TILE) * (H / TILE); // 256
    // grid.y = N (batch); both channels packed per block.

    dim3 grid(tilesPerPlane, N);
    ssim_tile_kernel<<<grid, THREADS, 0, stream>>>(x, y, partial, W, H);

    const int nPartial = tilesPerPlane * N;            // 8192
    const double inv_count = 1.0 / ((double)N * 2 * W * H);
    ssim_reduce_kernel<<<1, 256, 0, stream>>>(partial, nPartial, (float*)d_out,
                                              inv_count);
}